// Round 1
// baseline (1668.342 us; speedup 1.0000x reference)
//
#include <hip/hip_runtime.h>
#include <hip/hip_bf16.h>

#define B 64
#define N0 2048
#define DEG 16
#define IN_DIM 128
#define H 30
#define NH 11
#define K1 1844
#define K2 1660
#define K3 1494
#define NTOT (B * N0)        /* 131072 */
#define ETOT (NTOT * DEG)    /* 2097152 */

// ---------------------------------------------------------------------------
// Prep: fold layernorm gamma into layer-1 weights; combine rel/root weights
// into [K][60] blocks so the proj kernels read one contiguous uniform row.
//   Wc1[j][c] = (c<30 ? Wrel1[j][c] : Wroot1[j][c-30]) * ln_g[j]   (j<128)
//   S1[c]     = sum_j Wc1[j][c]
//   T1[c]     = sum_j ln_b[j]*W[j][c]  (+ brel1 for c>=30, the root/t half)
//   Wc2/Wc3   = [30][60] combined (no LN folding needed)
// ---------------------------------------------------------------------------
__global__ __launch_bounds__(256) void k_prep(
    const float* __restrict__ ln_g, const float* __restrict__ ln_b,
    const float* __restrict__ Wrel1, const float* __restrict__ brel1, const float* __restrict__ Wroot1,
    const float* __restrict__ Wrel2, const float* __restrict__ Wroot2,
    const float* __restrict__ Wrel3, const float* __restrict__ Wroot3,
    float* __restrict__ Wc1, float* __restrict__ S1, float* __restrict__ T1,
    float* __restrict__ Wc2, float* __restrict__ Wc3)
{
    int tid = threadIdx.x;
    for (int i = tid; i < IN_DIM * 60; i += 256) {
        int j = i / 60, c = i - j * 60;
        float w = (c < H) ? Wrel1[j * H + c] : Wroot1[j * H + (c - H)];
        Wc1[i] = w * ln_g[j];
    }
    if (tid < 60) {
        int c = tid;
        float s = 0.f, tt = 0.f;
        for (int j = 0; j < IN_DIM; ++j) {
            float w = (c < H) ? Wrel1[j * H + c] : Wroot1[j * H + (c - H)];
            s += w * ln_g[j];
            tt += w * ln_b[j];
        }
        S1[c] = s;
        T1[c] = (c < H) ? tt : tt + brel1[c - H];
    }
    for (int i = tid; i < H * 60; i += 256) {
        int j = i / 60, c = i - j * 60;
        Wc2[i] = (c < H) ? Wrel2[j * H + c] : Wroot2[j * H + (c - H)];
        Wc3[i] = (c < H) ? Wrel3[j * H + c] : Wroot3[j * H + (c - H)];
    }
}

// ---------------------------------------------------------------------------
// Layer 1: fused LayerNorm + dual projection. Thread-per-row, single pass.
// out_c = rstd*(A_c - mean*S_c) + T_c where A_c = sum_j x_j * Wc1[j][c].
// Exact grid (NTOT = 512*256): no divergence so W loads scalarize to s_load.
// ---------------------------------------------------------------------------
__global__ __launch_bounds__(256) void k_lnproj(
    const float* __restrict__ x, const float* __restrict__ Wc,
    const float* __restrict__ S, const float* __restrict__ T,
    float* __restrict__ r, float* __restrict__ t)
{
    int row = blockIdx.x * 256 + threadIdx.x;
    const float* xr = x + (size_t)row * IN_DIM;
    float acc[60];
#pragma unroll
    for (int c = 0; c < 60; ++c) acc[c] = 0.f;
    float sum = 0.f, sumsq = 0.f;
    for (int jb = 0; jb < IN_DIM; jb += 8) {
        float4 a0 = *(const float4*)(xr + jb);
        float4 a1 = *(const float4*)(xr + jb + 4);
        float xs[8] = {a0.x, a0.y, a0.z, a0.w, a1.x, a1.y, a1.z, a1.w};
#pragma unroll
        for (int u = 0; u < 8; ++u) {
            float xv = xs[u];
            sum += xv;
            sumsq += xv * xv;
            const float* wrow = Wc + (jb + u) * 60;
#pragma unroll
            for (int c = 0; c < 60; ++c) acc[c] += xv * wrow[c];
        }
    }
    float mean = sum * (1.f / 128.f);
    float var = sumsq * (1.f / 128.f) - mean * mean;
    float rstd = 1.0f / sqrtf(var + 1e-5f);
    int base = row * H;
#pragma unroll
    for (int c = 0; c < H; ++c)
        r[base + c] = rstd * (acc[c] - mean * S[c]) + T[c];
#pragma unroll
    for (int c = 0; c < H; ++c)
        t[base + c] = rstd * (acc[30 + c] - mean * S[30 + c]) + T[30 + c];
}

// ---------------------------------------------------------------------------
// Layers 2/3 projection: r = h@Wrel, t = h@Wroot + brel (Wc combined [30][60])
// ---------------------------------------------------------------------------
__global__ __launch_bounds__(256) void k_proj30(
    const float* __restrict__ h, const float* __restrict__ Wc,
    const float* __restrict__ brel, float* __restrict__ r, float* __restrict__ t)
{
    int row = blockIdx.x * 256 + threadIdx.x;
    const float* hr = h + (size_t)row * H;
    float hv[H];
#pragma unroll
    for (int j = 0; j < H; j += 2) {
        float2 v = *(const float2*)(hr + j);
        hv[j] = v.x; hv[j + 1] = v.y;
    }
    float acc[60];
#pragma unroll
    for (int c = 0; c < H; ++c) acc[c] = 0.f;
#pragma unroll
    for (int c = 0; c < H; ++c) acc[30 + c] = brel[c];
    for (int j = 0; j < H; ++j) {
        const float* wrow = Wc + j * 60;
        float xv = hv[j];
#pragma unroll
        for (int c = 0; c < 60; ++c) acc[c] += xv * wrow[c];
    }
    int base = row * H;
#pragma unroll
    for (int c = 0; c < H; ++c) { r[base + c] = acc[c]; t[base + c] = acc[30 + c]; }
}

// ---------------------------------------------------------------------------
// Edge aggregation: acc[dst] += r[src]*ew. Thread = (edge, feature).
// e = tid/30 via magic multiply (exact for tid < 2^32/14). ew==0 edges skipped
// (pooled-out edges) -- saves gather+atomic on ~19%/34% of edges in L2/L3.
// ---------------------------------------------------------------------------
__global__ void k_agg(const int* __restrict__ src, const int* __restrict__ dst,
                      const float* __restrict__ ew, const float* __restrict__ r,
                      float* __restrict__ acc)
{
    const int total = ETOT * H;
    int stride = gridDim.x * blockDim.x;
    for (int tid = blockIdx.x * blockDim.x + threadIdx.x; tid < total; tid += stride) {
        unsigned e = (unsigned)(((unsigned long long)(unsigned)tid * 2290649225ull) >> 36);
        int f = tid - (int)(e * 30u);
        float w = ew[e];
        if (w != 0.f) {
            float v = r[src[e] * H + f] * w;
            atomicAdd(acc + dst[e] * H + f, v);
        }
    }
}

__global__ void k_addrelu(float* __restrict__ acc, const float* __restrict__ t)
{
    int i = blockIdx.x * 256 + threadIdx.x;
    acc[i] = fmaxf(acc[i] + t[i], 0.f);
}

// score = tanh((h @ w) / ||w||)
__global__ __launch_bounds__(256) void k_score(
    const float* __restrict__ h, const float* __restrict__ w, float* __restrict__ score)
{
    int row = blockIdx.x * 256 + threadIdx.x;
    const float* hr = h + (size_t)row * H;
    float nw = 0.f, d = 0.f;
#pragma unroll
    for (int j = 0; j < H; ++j) {
        float wv = w[j];
        nw += wv * wv;
        d += hr[j] * wv;
    }
    score[row] = tanhf(d / sqrtf(nw));
}

// ---------------------------------------------------------------------------
// Per-graph top-k: bitonic sort of 2048 packed keys (desc score, asc idx) in
// LDS -- matches jax.lax.top_k total order incl. tie-break by lower index.
// Writes gated x_new (rank order) and newidx (old local -> rank, -1 dropped).
// ---------------------------------------------------------------------------
__global__ __launch_bounds__(256) void k_topk(
    const float* __restrict__ score, const float* __restrict__ h,
    float* __restrict__ xout, int* __restrict__ newidx, int n, int k)
{
    __shared__ unsigned long long keys[2048];
    int g = blockIdx.x;
    for (int i = threadIdx.x; i < 2048; i += 256) {
        unsigned long long key = ~0ull;
        if (i < n) {
            float s = score[g * n + i];
            if (s == 0.f) s = 0.f;                 // canonicalize -0 -> +0
            unsigned u = __float_as_uint(s);
            unsigned asc = (u & 0x80000000u) ? ~u : (u | 0x80000000u);
            unsigned desc = ~asc;                  // ascending key = descending score
            key = ((unsigned long long)desc << 32) | (unsigned)i;
        }
        keys[i] = key;
    }
    __syncthreads();
    for (int kk = 2; kk <= 2048; kk <<= 1) {
        for (int jj = kk >> 1; jj > 0; jj >>= 1) {
            for (int i = threadIdx.x; i < 2048; i += 256) {
                int ixj = i ^ jj;
                if (ixj > i) {
                    unsigned long long a = keys[i], b = keys[ixj];
                    bool up = ((i & kk) == 0);
                    if ((a > b) == up) { keys[i] = b; keys[ixj] = a; }
                }
            }
            __syncthreads();
        }
    }
    for (int i = threadIdx.x; i < n; i += 256) newidx[g * n + i] = -1;
    __syncthreads();
    for (int j = threadIdx.x; j < k; j += 256) {
        int idx = (int)(keys[j] & 0xffffffffu);
        newidx[g * n + idx] = j;
    }
    for (int m = threadIdx.x; m < k * H; m += 256) {
        int j = m / H, f = m - j * H;
        int idx = (int)(keys[j] & 0xffffffffu);
        float val = score[g * n + idx];
        xout[(g * k + j) * H + f] = h[(g * n + idx) * H + f] * val;
    }
}

// Edge remap after pooling (element-wise; safe in place).
__global__ void k_remap(const int* __restrict__ srcIn, const int* __restrict__ dstIn,
                        const float* __restrict__ ewIn, const int* __restrict__ newidx,
                        int* __restrict__ srcOut, int* __restrict__ dstOut,
                        float* __restrict__ ewOut, int nOld, int kNew)
{
    int e = blockIdx.x * 256 + threadIdx.x;
    int s = srcIn[e], d = dstIn[e];
    float w = ewIn[e];
    int g = s / nOld;
    int ns = newidx[g * nOld + (s - g * nOld)];
    int nd = newidx[g * nOld + (d % nOld)];
    bool keep = (ns >= 0) && (nd >= 0);
    srcOut[e] = keep ? g * kNew + ns : 0;
    dstOut[e] = keep ? g * kNew + nd : 0;
    ewOut[e] = keep ? w : 0.f;
}

// Per-graph readout: [max ; mean] over k rows -> out[g][0..59]
__global__ __launch_bounds__(256) void k_readout(
    const float* __restrict__ x, float* __restrict__ out, int k)
{
    __shared__ float smax[8][32], ssum[8][32];
    int g = blockIdx.x;
    int f = threadIdx.x & 31, rr = threadIdx.x >> 5;
    float mx = -INFINITY, sm = 0.f;
    if (f < H) {
        for (int row = rr; row < k; row += 8) {
            float v = x[(g * k + row) * H + f];
            mx = fmaxf(mx, v);
            sm += v;
        }
    }
    smax[rr][f] = mx; ssum[rr][f] = sm;
    __syncthreads();
    if (rr == 0 && f < H) {
        for (int q = 1; q < 8; ++q) { mx = fmaxf(mx, smax[q][f]); sm += ssum[q][f]; }
        out[g * 60 + f] = mx;
        out[g * 60 + 30 + f] = sm / (float)k;
    }
}

__global__ void k_z(const float* __restrict__ x1, const float* __restrict__ x2,
                    const float* __restrict__ x3, float* __restrict__ z)
{
    int i = blockIdx.x * 256 + threadIdx.x;
    z[i] = fmaxf(x1[i] + x2[i] + x3[i], 0.f);
}

// a1[h,b,o] = relu(sum_d z[b,d]*W1[h,d,o] + b1[h,o]),  o<240, d<60
__global__ __launch_bounds__(256) void k_mlp1(
    const float* __restrict__ z, const float* __restrict__ W,
    const float* __restrict__ bias, float* __restrict__ a)
{
    int hb = blockIdx.x, hh = hb >> 6, b = hb & 63;
    __shared__ float zr[60];
    if (threadIdx.x < 60) zr[threadIdx.x] = z[b * 60 + threadIdx.x];
    __syncthreads();
    int o = threadIdx.x;
    if (o < 240) {
        float acc = bias[hh * 240 + o];
        const float* Wp = W + hh * 60 * 240;
#pragma unroll
        for (int d = 0; d < 60; ++d) acc += zr[d] * Wp[d * 240 + o];
        a[(hh * B + b) * 240 + o] = fmaxf(acc, 0.f);
    }
}

// a2[h,b,p] = relu(sum_o a1[h,b,o]*W2[h,o,p] + b2[h,p]),  p<960, o<240
__global__ __launch_bounds__(256) void k_mlp2(
    const float* __restrict__ a1, const float* __restrict__ W,
    const float* __restrict__ bias, float* __restrict__ a2)
{
    int hb = blockIdx.x, hh = hb >> 6, b = hb & 63;
    __shared__ float ar[240];
    if (threadIdx.x < 240) ar[threadIdx.x] = a1[(hh * B + b) * 240 + threadIdx.x];
    __syncthreads();
    const float* Wp = W + hh * 240 * 960;
    for (int p = threadIdx.x; p < 960; p += 256) {
        float acc = bias[hh * 960 + p];
        for (int o = 0; o < 240; ++o) acc += ar[o] * Wp[o * 960 + p];
        a2[(hh * B + b) * 960 + p] = fmaxf(acc, 0.f);
    }
}

// out[h,b,q] = sum_p a2[h,b,p]*W3[h,p,q] + b3[h,q],  q<8, p<960
__global__ __launch_bounds__(64) void k_mlp3(
    const float* __restrict__ a2, const float* __restrict__ W,
    const float* __restrict__ bias, float* __restrict__ out)
{
    int hb = blockIdx.x, hh = hb >> 6, b = hb & 63;
    __shared__ float ar[960];
    __shared__ float part[64];
    for (int i = threadIdx.x; i < 960; i += 64) ar[i] = a2[(hh * B + b) * 960 + i];
    __syncthreads();
    int q = threadIdx.x & 7, c = threadIdx.x >> 3;
    const float* Wp = W + hh * 960 * 8;
    float acc = 0.f;
    for (int p = c; p < 960; p += 8) acc += ar[p] * Wp[p * 8 + q];
    part[threadIdx.x] = acc;
    __syncthreads();
    if (threadIdx.x < 8) {
        float s = bias[hh * 8 + threadIdx.x];
        for (int cc = 0; cc < 8; ++cc) s += part[cc * 8 + threadIdx.x];
        out[(hh * B + b) * 8 + threadIdx.x] = s;
    }
}

// ---------------------------------------------------------------------------
extern "C" void kernel_launch(void* const* d_in, const int* in_sizes, int n_in,
                              void* d_out, int out_size, void* d_ws, size_t ws_size,
                              hipStream_t stream)
{
    const float* x       = (const float*)d_in[0];
    const int*   eidx    = (const int*)d_in[1];
    const int*   src0    = eidx;
    const int*   dst0    = eidx + ETOT;
    const float* ew0     = (const float*)d_in[2];
    const float* ln_g    = (const float*)d_in[4];
    const float* ln_b    = (const float*)d_in[5];
    const float* W_rel1  = (const float*)d_in[6];
    const float* b_rel1  = (const float*)d_in[7];
    const float* W_root1 = (const float*)d_in[8];
    const float* W_rel2  = (const float*)d_in[9];
    const float* b_rel2  = (const float*)d_in[10];
    const float* W_root2 = (const float*)d_in[11];
    const float* W_rel3  = (const float*)d_in[12];
    const float* b_rel3  = (const float*)d_in[13];
    const float* W_root3 = (const float*)d_in[14];
    const float* pool_w1 = (const float*)d_in[15];
    const float* pool_w2 = (const float*)d_in[16];
    const float* pool_w3 = (const float*)d_in[17];
    const float* head_W1 = (const float*)d_in[18];
    const float* head_b1 = (const float*)d_in[19];
    const float* head_W2 = (const float*)d_in[20];
    const float* head_b2 = (const float*)d_in[21];
    const float* head_W3 = (const float*)d_in[22];
    const float* head_b3 = (const float*)d_in[23];

    // workspace carve (total ~92.6 MB)
    float* ws     = (float*)d_ws;
    float* rbuf   = ws;                          // NTOT*30
    float* tbuf   = rbuf + (size_t)NTOT * H;     // NTOT*30
    float* abuf   = tbuf + (size_t)NTOT * H;     // NTOT*30 (acc -> h)
    float* xp     = abuf + (size_t)NTOT * H;     // NTOT*30 (pooled x)
    float* score  = xp + (size_t)NTOT * H;       // NTOT
    int*   newidx = (int*)(score + NTOT);        // NTOT
    int*   srcw   = newidx + NTOT;               // ETOT
    int*   dstw   = srcw + ETOT;                 // ETOT
    float* eww    = (float*)(dstw + ETOT);       // ETOT
    float* x1     = eww + ETOT;                  // B*60
    float* x2     = x1 + B * 60;
    float* x3     = x2 + B * 60;
    float* zb     = x3 + B * 60;
    float* a1     = zb + B * 60;                 // 11*64*240
    float* a2     = a1 + NH * B * 240;           // 11*64*960
    float* Wc1    = a2 + NH * B * 960;           // 128*60
    float* S1     = Wc1 + IN_DIM * 60;           // 60
    float* T1     = S1 + 60;                     // 60
    float* Wc2    = T1 + 60;                     // 30*60
    float* Wc3    = Wc2 + H * 60;                // 30*60

    const int N2 = B * K1;   // 118016 = 461*256
    const int N3 = B * K2;   // 106240 = 415*256

    k_prep<<<1, 256, 0, stream>>>(ln_g, ln_b, W_rel1, b_rel1, W_root1,
                                  W_rel2, W_root2, W_rel3, W_root3,
                                  Wc1, S1, T1, Wc2, Wc3);

    // ---- layer 1 ----
    k_lnproj<<<NTOT / 256, 256, 0, stream>>>(x, Wc1, S1, T1, rbuf, tbuf);
    hipMemsetAsync(abuf, 0, (size_t)NTOT * H * 4, stream);
    k_agg<<<4096, 256, 0, stream>>>(src0, dst0, ew0, rbuf, abuf);
    k_addrelu<<<NTOT * H / 256, 256, 0, stream>>>(abuf, tbuf);
    k_score<<<NTOT / 256, 256, 0, stream>>>(abuf, pool_w1, score);
    k_topk<<<B, 256, 0, stream>>>(score, abuf, xp, newidx, N0, K1);
    k_remap<<<ETOT / 256, 256, 0, stream>>>(src0, dst0, ew0, newidx, srcw, dstw, eww, N0, K1);
    k_readout<<<B, 256, 0, stream>>>(xp, x1, K1);

    // ---- layer 2 ----
    k_proj30<<<N2 / 256, 256, 0, stream>>>(xp, Wc2, b_rel2, rbuf, tbuf);
    hipMemsetAsync(abuf, 0, (size_t)N2 * H * 4, stream);
    k_agg<<<4096, 256, 0, stream>>>(srcw, dstw, eww, rbuf, abuf);
    k_addrelu<<<N2 * H / 256, 256, 0, stream>>>(abuf, tbuf);
    k_score<<<N2 / 256, 256, 0, stream>>>(abuf, pool_w2, score);
    k_topk<<<B, 256, 0, stream>>>(score, abuf, xp, newidx, K1, K2);
    k_remap<<<ETOT / 256, 256, 0, stream>>>(srcw, dstw, eww, newidx, srcw, dstw, eww, K1, K2);
    k_readout<<<B, 256, 0, stream>>>(xp, x2, K2);

    // ---- layer 3 ----
    k_proj30<<<N3 / 256, 256, 0, stream>>>(xp, Wc3, b_rel3, rbuf, tbuf);
    hipMemsetAsync(abuf, 0, (size_t)N3 * H * 4, stream);
    k_agg<<<4096, 256, 0, stream>>>(srcw, dstw, eww, rbuf, abuf);
    k_addrelu<<<N3 * H / 256, 256, 0, stream>>>(abuf, tbuf);
    k_score<<<N3 / 256, 256, 0, stream>>>(abuf, pool_w3, score);
    k_topk<<<B, 256, 0, stream>>>(score, abuf, xp, newidx, K2, K3);
    k_readout<<<B, 256, 0, stream>>>(xp, x3, K3);

    // ---- heads ----
    k_z<<<B * 60 / 256, 256, 0, stream>>>(x1, x2, x3, zb);
    k_mlp1<<<NH * B, 256, 0, stream>>>(zb, head_W1, head_b1, a1);
    k_mlp2<<<NH * B, 256, 0, stream>>>(a1, head_W2, head_b2, a2);
    k_mlp3<<<NH * B, 64, 0, stream>>>(a2, head_W3, head_b3, (float*)d_out);
}